// Round 5
// baseline (419.261 us; speedup 1.0000x reference)
//
#include <hip/hip_runtime.h>
#include <math.h>

#define IN_DIM 28
#define BOND   10
#define OUT_D  10
#define BLOCK  256
#define SPT    4                 // samples per thread
#define H0_STRIDE 11             // odd stride -> conflict-free h0 spill

typedef _Float16 h2 __attribute__((ext_vector_type(2)));
typedef __fp16   h2fp __attribute__((ext_vector_type(2)));
struct __attribute__((aligned(16))) H2x4 { h2 v[4]; };   // one ds_read_b128

__device__ __forceinline__ float fdot2(h2 a, h2 b, float c) {
#if __has_builtin(__builtin_amdgcn_fdot2)
    return __builtin_amdgcn_fdot2(__builtin_bit_cast(h2fp, a),
                                  __builtin_bit_cast(h2fp, b), c, false);
#else
    return c + (float)a.x * (float)b.x + (float)a.y * (float)b.y;
#endif
}

__device__ __forceinline__ h2 pk16(float a, float b) {
#if __has_builtin(__builtin_amdgcn_cvt_pkrtz)
    return __builtin_bit_cast(h2, __builtin_amdgcn_cvt_pkrtz(a, b));
#else
    h2 r; r.x = (_Float16)a; r.y = (_Float16)b; return r;
#endif
}

// One thread = 4 samples, f16 dot2 math. Weights in LDS as packed half2 pairs;
// every ds_read_b128 (4 half2) feeds 16 v_dot2 (32 cyc VALU) -> read latency
// hidden. All register arrays compile-time indexed; h0 (runtime b in the
// rolled b-loop) round-trips through LDS at odd stride.
__global__ __launch_bounds__(BLOCK, 3) void tn_kernel(
    const float* __restrict__ x,     // [N, 56]
    const float* __restrict__ t0,    // [28,10]
    const float* __restrict__ t1,    // [28,10,10]
    const float* __restrict__ bias,  // [10]
    float* __restrict__ out,         // [N,10]
    int n_total)
{
    __shared__ __align__(16) h2 lt0h[IN_DIM / 2 * BOND];              // 140: [ip][b]
    __shared__ __align__(16) h2 lt1h[BOND * IN_DIM / 2 * OUT_D];      // 1400: [b][jp][o]
    __shared__ float lbias[OUT_D];
    __shared__ float lh0[SPT * BLOCK * H0_STRIDE];                    // 45 KB spill

    const int tid = threadIdx.x;

    // ---- stage + f32->f16 pack the weights (one-time) ----
    for (int idx = tid; idx < 140; idx += BLOCK) {
        const int ip = idx / 10, b = idx - ip * 10;
        lt0h[idx] = pk16(t0[(2 * ip) * BOND + b], t0[(2 * ip + 1) * BOND + b]);
    }
    for (int idx = tid; idx < 1400; idx += BLOCK) {
        const int b = idx / 140;
        const int r = idx - b * 140;
        const int jp = r / 10, o = r - jp * 10;
        lt1h[idx] = pk16(t1[((2 * jp) * BOND + b) * OUT_D + o],
                         t1[((2 * jp + 1) * BOND + b) * OUT_D + o]);
    }
    if (tid < OUT_D) lbias[tid] = bias[tid];

    const int base = blockIdx.x * (BLOCK * SPT);

    // ---- load 4 samples' rows (global, no LDS dep -> issue before barrier) ----
    float4 q[SPT][14];
#pragma unroll
    for (int s = 0; s < SPT; ++s) {
        const int n = base + s * BLOCK + tid;
        const float4* __restrict__ row =
            reinterpret_cast<const float4*>(x + (size_t)n * (2 * IN_DIM));
#pragma unroll
        for (int k = 0; k < 14; ++k) q[s][k] = row[k];
    }

    __syncthreads();

    // ---- pack x to half2: x0h[s][ip], x1h[s][jp] (compile-time indexed) ----
    h2 x0h[SPT][14], x1h[SPT][14];
#pragma unroll
    for (int s = 0; s < SPT; ++s) {
#pragma unroll
        for (int k = 0; k < 7; ++k) {             // first 28 floats = q[s][0..6]
            x0h[s][2 * k]     = pk16(q[s][k].x, q[s][k].y);
            x0h[s][2 * k + 1] = pk16(q[s][k].z, q[s][k].w);
        }
#pragma unroll
        for (int k = 0; k < 7; ++k) {             // last 28 floats = q[s][7..13]
            x1h[s][2 * k]     = pk16(q[s][7 + k].x, q[s][7 + k].y);
            x1h[s][2 * k + 1] = pk16(q[s][7 + k].z, q[s][7 + k].w);
        }
    }

    // ---- h0[s][b] = sum_ip dot2(x0h[s][ip], t0h[ip][b]) ----
    float h0[SPT][BOND];
#pragma unroll
    for (int s = 0; s < SPT; ++s)
#pragma unroll
        for (int b = 0; b < BOND; ++b) h0[s][b] = 0.0f;
    {
        const H2x4* __restrict__ w0 = reinterpret_cast<const H2x4*>(lt0h);
#pragma unroll
        for (int c = 0; c < 35; ++c) {            // 140 h2 = 35 b128
            const H2x4 w = w0[c];
#pragma unroll
            for (int k = 0; k < 4; ++k) {
                const int e = 4 * c + k;          // e = ip*10 + b
                const int ip = e / 10, b = e - ip * 10;
#pragma unroll
                for (int s = 0; s < SPT; ++s)
                    h0[s][b] = fdot2(x0h[s][ip], w.v[k], h0[s][b]);
            }
        }
    }
    // spill h0 (runtime-b access in the rolled loop); stride 11 -> conflict-free
#pragma unroll
    for (int s = 0; s < SPT; ++s)
#pragma unroll
        for (int b = 0; b < BOND; ++b)
            lh0[(s * BLOCK + tid) * H0_STRIDE + b] = h0[s][b];

    // ---- c[s][o] = bias[o] + sum_b h0[s][b] * sum_jp dot2(x1h[s][jp], t1h[b][jp][o]) ----
    float acc[SPT][OUT_D];
#pragma unroll
    for (int s = 0; s < SPT; ++s)
#pragma unroll
        for (int o = 0; o < OUT_D; ++o) acc[s][o] = lbias[o];

#pragma unroll 1   // rolled: body ~5 KB, stays in L1I
    for (int b = 0; b < BOND; ++b) {
        float hb[SPT];
#pragma unroll
        for (int s = 0; s < SPT; ++s)
            hb[s] = lh0[(s * BLOCK + tid) * H0_STRIDE + b];

        const H2x4* __restrict__ wb =
            reinterpret_cast<const H2x4*>(&lt1h[b * 140]);   // 560 B, 16-aligned
        float g[SPT][OUT_D];
#pragma unroll
        for (int s = 0; s < SPT; ++s)
#pragma unroll
            for (int o = 0; o < OUT_D; ++o) g[s][o] = 0.0f;
#pragma unroll
        for (int c = 0; c < 35; ++c) {            // 140 h2 per b = 35 b128
            const H2x4 w = wb[c];
#pragma unroll
            for (int k = 0; k < 4; ++k) {
                const int e = 4 * c + k;          // e = jp*10 + o
                const int jp = e / 10, o = e - jp * 10;
#pragma unroll
                for (int s = 0; s < SPT; ++s)
                    g[s][o] = fdot2(x1h[s][jp], w.v[k], g[s][o]);
            }
        }
#pragma unroll
        for (int s = 0; s < SPT; ++s)
#pragma unroll
            for (int o = 0; o < OUT_D; ++o)
                acc[s][o] = fmaf(hb[s], g[s][o], acc[s][o]);
    }

    // ---- sigmoid + store (rows 40 B, 8-aligned -> float2 stores) ----
#pragma unroll
    for (int s = 0; s < SPT; ++s) {
        const int n = base + s * BLOCK + tid;
        if (n < n_total) {
            float2* __restrict__ op =
                reinterpret_cast<float2*>(out + (size_t)n * OUT_D);
#pragma unroll
            for (int o = 0; o < OUT_D; o += 2) {
                float2 r;
                r.x = 1.0f / (1.0f + __expf(-acc[s][o]));
                r.y = 1.0f / (1.0f + __expf(-acc[s][o + 1]));
                op[o >> 1] = r;
            }
        }
    }
}

extern "C" void kernel_launch(void* const* d_in, const int* in_sizes, int n_in,
                              void* d_out, int out_size, void* d_ws, size_t ws_size,
                              hipStream_t stream) {
    const float* x    = (const float*)d_in[0];
    const float* t0   = (const float*)d_in[1];
    const float* t1   = (const float*)d_in[2];
    const float* bias = (const float*)d_in[3];
    float* out        = (float*)d_out;

    const int n_total = in_sizes[0] / (2 * IN_DIM);
    const int grid = (n_total + BLOCK * SPT - 1) / (BLOCK * SPT);
    tn_kernel<<<grid, BLOCK, 0, stream>>>(x, t0, t1, bias, out, n_total);
}